// Round 3
// baseline (292.015 us; speedup 1.0000x reference)
//
#include <hip/hip_runtime.h>
#include <math.h>

#define C_DIM 128
#define DQ 32        // C/4 float4s per row
#define DEG 64
#define NEG_SLOPE 0.2f

// ---------------------------------------------------------------------------
// Streaming pre-pass: sum[i] = nf[i] + mem[i]  (halves the random-gather
// footprint AND leaves it hot in L2/L3 for the detector).
// Block 0 additionally computes:
//   combo[c]  = sum_k W_max[c][k] * W_score[k]
//   combo[128]= sum_k b_max[k] * W_score[k] + b_score
// ---------------------------------------------------------------------------
__global__ __launch_bounds__(256)
void fuse_sum_kernel(const float4* __restrict__ nf4,
                     const float4* __restrict__ mem4,
                     float4* __restrict__ sum4, long n4,
                     const float* __restrict__ W_max,
                     const float* __restrict__ b_max,
                     const float* __restrict__ W_score,
                     const float* __restrict__ b_score,
                     float* __restrict__ combo) {
    const long stride = (long)gridDim.x * 256;
    for (long i = (long)blockIdx.x * 256 + threadIdx.x; i < n4; i += stride) {
        const float4 a = nf4[i];
        const float4 b = mem4[i];
        sum4[i] = make_float4(a.x + b.x, a.y + b.y, a.z + b.z, a.w + b.w);
    }
    if (blockIdx.x == 0) {
        const int c = threadIdx.x;
        __shared__ float red[C_DIM];
        if (c < C_DIM) {
            float acc = 0.f;
            #pragma unroll 4
            for (int k = 0; k < C_DIM; ++k)
                acc += W_max[c * C_DIM + k] * W_score[k];
            combo[c] = acc;
            red[c] = b_max[c] * W_score[c];
        }
        __syncthreads();
        for (int off = 64; off > 0; off >>= 1) {
            if (c < off) red[c] += red[c + off];
            __syncthreads();
        }
        if (c == 0) combo[C_DIM] = red[0] + b_score[0];
    }
}

// ---------------------------------------------------------------------------
// Main fused kernel: one block per source node (8192 blocks x 256 threads).
// Thread t: q = t&31 -> channels [4q,4q+4); rows j = g*8 + i  (g = t>>5).
// FUSED: gather from precomputed sum array (1 load/row-slice).
// !FUSED: gather nf + mem separately (fallback when ws too small).
// Tile kept in REGISTERS; an asm memory barrier prevents the compiler from
// rematerializing the global loads in the pooling pass (round-1 bug: VGPR=28
// proved remat; here VGPR~60 -> still 8 waves/SIMD).
// ---------------------------------------------------------------------------
template <bool FUSED>
__global__ __launch_bounds__(256)
void detector_kernel(const float* __restrict__ src,   // sum (FUSED) or nf
                     const float* __restrict__ mem,   // unused when FUSED
                     const float* __restrict__ W_score,
                     const float* __restrict__ W_fit,
                     const float* __restrict__ b_fit,
                     const int* __restrict__ neighbors,
                     const float* __restrict__ combo,
                     float* __restrict__ out_cf,
                     float* __restrict__ out_score,
                     float* __restrict__ out_fit) {
    __shared__ float4 red[256];            // 4 KB cross-group reduction
    __shared__ float  s_raw[DEG];          // per-slot neighbor-half score dot
    __shared__ float  sc[DEG];             // softmax scores
    __shared__ float  t1_sh;               // center-half score contribution

    const int tid = threadIdx.x;
    const int n   = blockIdx.x;
    const int q   = tid & 31;
    const int g   = tid >> 5;

    // 8 contiguous neighbor ids for this thread's rows j = g*8 .. g*8+7
    const int4* nb4 = (const int4*)(neighbors + n * DEG + g * 8);
    const int4 nba = nb4[0];
    const int4 nbb = nb4[1];
    const int ids[8] = {nba.x, nba.y, nba.z, nba.w, nbb.x, nbb.y, nbb.z, nbb.w};

    // neighbor-half score weights for this thread's 4 channels
    const float4 wsb = ((const float4*)(W_score + C_DIM))[q];

    const float4* src4 = (const float4*)src;
    const float4* mem4 = (const float4*)mem;

    float4 v[8];
    float4 mx = make_float4(-INFINITY, -INFINITY, -INFINITY, -INFINITY);

    #pragma unroll
    for (int i = 0; i < 8; ++i) {
        const int j = g * 8 + i;
        const long node = ids[i];
        float4 vv = src4[node * DQ + q];
        if (!FUSED) {
            const float4 b = mem4[node * DQ + q];
            vv.x += b.x; vv.y += b.y; vv.z += b.z; vv.w += b.w;
        }
        v[i] = vv;
        mx.x = fmaxf(mx.x, vv.x); mx.y = fmaxf(mx.y, vv.y);
        mx.z = fmaxf(mx.z, vv.z); mx.w = fmaxf(mx.w, vv.w);
        // per-row score dot (neighbor half), reduced over the 32-lane group
        float p = vv.x * wsb.x + vv.y * wsb.y + vv.z * wsb.z + vv.w * wsb.w;
        p += __shfl_xor(p, 1);
        p += __shfl_xor(p, 2);
        p += __shfl_xor(p, 4);
        p += __shfl_xor(p, 8);
        p += __shfl_xor(p, 16);
        if (q == 0) s_raw[j] = p;
    }
    // Compiler barrier: forbid sinking/remat of the gather loads into pass 2.
    asm volatile("" ::: "memory");

    red[tid] = mx;
    __syncthreads();

    // channel max across the 8 row-groups + center-half score t1 = mf . combo
    if (tid < 32) {
        float4 f = red[tid];
        #pragma unroll
        for (int r = 1; r < 8; ++r) {
            const float4 o = red[tid + 32 * r];
            f.x = fmaxf(f.x, o.x); f.y = fmaxf(f.y, o.y);
            f.z = fmaxf(f.z, o.z); f.w = fmaxf(f.w, o.w);
        }
        const float4 wc = ((const float4*)combo)[tid];
        float t1 = f.x * wc.x + f.y * wc.y + f.z * wc.z + f.w * wc.w;
        t1 += __shfl_xor(t1, 1);
        t1 += __shfl_xor(t1, 2);
        t1 += __shfl_xor(t1, 4);
        t1 += __shfl_xor(t1, 8);
        t1 += __shfl_xor(t1, 16);
        if (tid == 0) t1_sh = t1 + combo[C_DIM];  // + b_combo (incl. b_score)
    }
    __syncthreads();

    // leaky-relu + softmax over the 64 slots (single wave)
    if (tid < DEG) {
        float s = t1_sh + s_raw[tid];
        s = (s >= 0.f) ? s : NEG_SLOPE * s;
        float m = s;
        #pragma unroll
        for (int msk = 1; msk <= 32; msk <<= 1)
            m = fmaxf(m, __shfl_xor(m, msk));
        const float ex = __expf(s - m);
        float d = ex;
        #pragma unroll
        for (int msk = 1; msk <= 32; msk <<= 1)
            d += __shfl_xor(d, msk);
        const float sv = ex / d;
        sc[tid] = sv;
        out_score[n * DEG + tid] = sv;
    }
    __syncthreads();

    // score-weighted pooling from the register tile
    float4 acc = make_float4(0.f, 0.f, 0.f, 0.f);
    #pragma unroll
    for (int i = 0; i < 8; ++i) {
        const float w = sc[g * 8 + i];
        acc.x += v[i].x * w; acc.y += v[i].y * w;
        acc.z += v[i].z * w; acc.w += v[i].w * w;
    }
    red[tid] = acc;
    __syncthreads();

    if (tid < 32) {
        float4 f = red[tid];
        #pragma unroll
        for (int r = 1; r < 8; ++r) {
            const float4 o = red[tid + 32 * r];
            f.x += o.x; f.y += o.y; f.z += o.z; f.w += o.w;
        }
        ((float4*)(out_cf + (long)n * C_DIM))[tid] = f;
        const float4 wf = ((const float4*)W_fit)[tid];
        float fp = f.x * wf.x + f.y * wf.y + f.z * wf.z + f.w * wf.w;
        fp += __shfl_xor(fp, 1);
        fp += __shfl_xor(fp, 2);
        fp += __shfl_xor(fp, 4);
        fp += __shfl_xor(fp, 8);
        fp += __shfl_xor(fp, 16);
        if (tid == 0)
            out_fit[n] = 1.f / (1.f + __expf(-(fp + b_fit[0])));
    }
}

// old tiny precompute (fallback path only)
__global__ void precompute_kernel(const float* __restrict__ W_max,
                                  const float* __restrict__ b_max,
                                  const float* __restrict__ W_score,
                                  const float* __restrict__ b_score,
                                  float* __restrict__ combo) {
    const int c = threadIdx.x;
    float acc = 0.f;
    #pragma unroll 4
    for (int k = 0; k < C_DIM; ++k)
        acc += W_max[c * C_DIM + k] * W_score[k];
    combo[c] = acc;
    __shared__ float red[C_DIM];
    red[c] = b_max[c] * W_score[c];
    __syncthreads();
    for (int off = 64; off > 0; off >>= 1) {
        if (c < off) red[c] += red[c + off];
        __syncthreads();
    }
    if (c == 0) combo[C_DIM] = red[0] + b_score[0];
}

extern "C" void kernel_launch(void* const* d_in, const int* in_sizes, int n_in,
                              void* d_out, int out_size, void* d_ws, size_t ws_size,
                              hipStream_t stream) {
    const float* node_features = (const float*)d_in[0];
    const float* memory        = (const float*)d_in[1];
    const float* W_max         = (const float*)d_in[2];
    const float* b_max         = (const float*)d_in[3];
    const float* W_score       = (const float*)d_in[4];
    const float* b_score       = (const float*)d_in[5];
    const float* W_fit         = (const float*)d_in[6];
    const float* b_fit         = (const float*)d_in[7];
    const int*   neighbors     = (const int*)d_in[8];
    // d_in[9] = seg = repeat(arange(nodes), DEG): slot e belongs to node e/DEG

    const long n_total  = in_sizes[0] / C_DIM;     // 200000
    const long n_elem   = (long)in_sizes[0];       // n_total * C
    const int  nodes    = in_sizes[8] / DEG;       // 8192
    const long n4       = n_elem / 4;

    float* combo = (float*)d_ws;                   // [129] (+pad to 512)
    float* sum   = combo + 512;                    // [n_total*C] fp32, 16B-aligned
    const size_t need = (size_t)(512 + n_elem) * sizeof(float);

    float* out_cf    = (float*)d_out;                       // [nodes,128]
    float* out_score = out_cf + (long)nodes * C_DIM;        // [nodes,64]
    float* out_fit   = out_score + (long)nodes * DEG;       // [nodes]

    if (ws_size >= need) {
        fuse_sum_kernel<<<4096, 256, 0, stream>>>(
            (const float4*)node_features, (const float4*)memory,
            (float4*)sum, n4, W_max, b_max, W_score, b_score, combo);
        detector_kernel<true><<<nodes, 256, 0, stream>>>(
            sum, nullptr, W_score, W_fit, b_fit, neighbors, combo,
            out_cf, out_score, out_fit);
    } else {
        precompute_kernel<<<1, C_DIM, 0, stream>>>(W_max, b_max, W_score,
                                                   b_score, combo);
        detector_kernel<false><<<nodes, 256, 0, stream>>>(
            node_features, memory, W_score, W_fit, b_fit, neighbors, combo,
            out_cf, out_score, out_fit);
    }
}

// Round 4
// 263.278 us; speedup vs baseline: 1.1092x; 1.1092x over previous
//
#include <hip/hip_runtime.h>
#include <hip/hip_fp16.h>
#include <math.h>

#define C_DIM 128
#define DEG 64
#define NEG_SLOPE 0.2f

typedef float nfloat4 __attribute__((ext_vector_type(4)));

// ---------------------------------------------------------------------------
// Streaming pre-pass: sum[i] = (half)(nf[i] + mem[i]).
//  - fp16 halves the write AND halves the detector's random-gather footprint
//    (51 MB -> fully L3-resident after this kernel).
//  - nontemporal loads: nf/mem are dead after this pass; don't let 205 MB of
//    streamed input evict the sum lines from L3.
// Block 0 additionally computes combo[c] = sum_k W_max[c][k]*W_score[k],
// combo[128] = b_max . W_score + b_score.
// ---------------------------------------------------------------------------
__global__ __launch_bounds__(256)
void fuse_sum_half_kernel(const nfloat4* __restrict__ nf4,
                          const nfloat4* __restrict__ mem4,
                          nfloat4* __restrict__ sumh, long n8,
                          const float* __restrict__ W_max,
                          const float* __restrict__ b_max,
                          const float* __restrict__ W_score,
                          const float* __restrict__ b_score,
                          float* __restrict__ combo) {
    const long stride = (long)gridDim.x * 256;
    for (long i = (long)blockIdx.x * 256 + threadIdx.x; i < n8; i += stride) {
        const nfloat4 a0 = __builtin_nontemporal_load(nf4 + 2 * i);
        const nfloat4 a1 = __builtin_nontemporal_load(nf4 + 2 * i + 1);
        const nfloat4 b0 = __builtin_nontemporal_load(mem4 + 2 * i);
        const nfloat4 b1 = __builtin_nontemporal_load(mem4 + 2 * i + 1);
        const nfloat4 s0 = a0 + b0;
        const nfloat4 s1 = a1 + b1;
        __half2 h[4];
        h[0] = __floats2half2_rn(s0.x, s0.y);
        h[1] = __floats2half2_rn(s0.z, s0.w);
        h[2] = __floats2half2_rn(s1.x, s1.y);
        h[3] = __floats2half2_rn(s1.z, s1.w);
        sumh[i] = *(const nfloat4*)h;   // normal store: keep in L2/L3
    }
    if (blockIdx.x == 0) {
        const int c = threadIdx.x;
        __shared__ float red[C_DIM];
        if (c < C_DIM) {
            float acc = 0.f;
            #pragma unroll 4
            for (int k = 0; k < C_DIM; ++k)
                acc += W_max[c * C_DIM + k] * W_score[k];
            combo[c] = acc;
            red[c] = b_max[c] * W_score[c];
        }
        __syncthreads();
        for (int off = 64; off > 0; off >>= 1) {
            if (c < off) red[c] += red[c + off];
            __syncthreads();
        }
        if (c == 0) combo[C_DIM] = red[0] + b_score[0];
    }
}

// ---------------------------------------------------------------------------
// Main fused kernel (fp16 sum): one block per node, 256 threads.
// q = tid&15 -> 16B chunk (8 channels), g = tid>>4 -> rows 4g..4g+3.
// 4 x 16B gather loads/thread; tile kept in registers as halves.
// ---------------------------------------------------------------------------
__global__ __launch_bounds__(256)
void detector_half_kernel(const float4* __restrict__ sum4,   // 8 halves each
                          const float* __restrict__ W_score,
                          const float* __restrict__ W_fit,
                          const float* __restrict__ b_fit,
                          const int* __restrict__ neighbors,
                          const float* __restrict__ combo,
                          float* __restrict__ out_cf,
                          float* __restrict__ out_score,
                          float* __restrict__ out_fit) {
    __shared__ float4 red4[256][2];   // 8 KB: per-thread 8 floats
    __shared__ float  chan[C_DIM];    // per-channel scratch
    __shared__ float  s_raw[DEG];
    __shared__ float  sc[DEG];

    const int tid = threadIdx.x;
    const int n   = blockIdx.x;
    const int q   = tid & 15;
    const int g   = tid >> 4;

    const int4 nb = ((const int4*)(neighbors + n * DEG))[g];  // rows 4g..4g+3
    const int ids[4] = {nb.x, nb.y, nb.z, nb.w};

    // neighbor-half score weights for channels [8q, 8q+8)
    const float4 wsb0 = ((const float4*)(W_score + C_DIM))[2 * q];
    const float4 wsb1 = ((const float4*)(W_score + C_DIM))[2 * q + 1];

    float4 vh[4];                     // 4 rows x 8 halves (registers)
    float mx[8];
    #pragma unroll
    for (int k = 0; k < 8; ++k) mx[k] = -INFINITY;

    #pragma unroll
    for (int i = 0; i < 4; ++i) {
        const long node = ids[i];
        const float4 hv = sum4[node * 16 + q];
        vh[i] = hv;
        const __half2* hp = (const __half2*)&hv;
        const float2 f0 = __half22float2(hp[0]);
        const float2 f1 = __half22float2(hp[1]);
        const float2 f2 = __half22float2(hp[2]);
        const float2 f3 = __half22float2(hp[3]);
        mx[0] = fmaxf(mx[0], f0.x); mx[1] = fmaxf(mx[1], f0.y);
        mx[2] = fmaxf(mx[2], f1.x); mx[3] = fmaxf(mx[3], f1.y);
        mx[4] = fmaxf(mx[4], f2.x); mx[5] = fmaxf(mx[5], f2.y);
        mx[6] = fmaxf(mx[6], f3.x); mx[7] = fmaxf(mx[7], f3.y);
        float p = f0.x * wsb0.x + f0.y * wsb0.y + f1.x * wsb0.z + f1.y * wsb0.w
                + f2.x * wsb1.x + f2.y * wsb1.y + f3.x * wsb1.z + f3.y * wsb1.w;
        p += __shfl_xor(p, 1);
        p += __shfl_xor(p, 2);
        p += __shfl_xor(p, 4);
        p += __shfl_xor(p, 8);
        if (q == 0) s_raw[g * 4 + i] = p;
    }
    asm volatile("" ::: "memory");   // forbid remat of gather loads

    red4[tid][0] = make_float4(mx[0], mx[1], mx[2], mx[3]);
    red4[tid][1] = make_float4(mx[4], mx[5], mx[6], mx[7]);
    __syncthreads();

    // per-channel max over the 16 row-groups; chan[c] = maxfeat[c]*combo[c]
    const float* rp = (const float*)red4;
    if (tid < C_DIM) {
        const int ch = tid >> 3;     // chunk
        const int k  = tid & 7;
        float f = rp[(0 * 16 + ch) * 8 + k];
        #pragma unroll
        for (int g2 = 1; g2 < 16; ++g2)
            f = fmaxf(f, rp[(g2 * 16 + ch) * 8 + k]);
        chan[tid] = f * combo[tid];
    }
    __syncthreads();

    // center-half score + leaky-relu + softmax (single wave, all via shfl)
    if (tid < DEG) {
        float t1 = chan[tid] + chan[tid + 64];
        #pragma unroll
        for (int msk = 1; msk <= 32; msk <<= 1)
            t1 += __shfl_xor(t1, msk);
        t1 += combo[C_DIM];
        float s = t1 + s_raw[tid];
        s = (s >= 0.f) ? s : NEG_SLOPE * s;
        float m = s;
        #pragma unroll
        for (int msk = 1; msk <= 32; msk <<= 1)
            m = fmaxf(m, __shfl_xor(m, msk));
        const float ex = __expf(s - m);
        float d = ex;
        #pragma unroll
        for (int msk = 1; msk <= 32; msk <<= 1)
            d += __shfl_xor(d, msk);
        const float sv = ex / d;
        sc[tid] = sv;
        out_score[n * DEG + tid] = sv;
    }
    __syncthreads();

    // score-weighted pooling from register tile
    float acc[8] = {0.f, 0.f, 0.f, 0.f, 0.f, 0.f, 0.f, 0.f};
    #pragma unroll
    for (int i = 0; i < 4; ++i) {
        const float w = sc[g * 4 + i];
        const __half2* hp = (const __half2*)&vh[i];
        const float2 f0 = __half22float2(hp[0]);
        const float2 f1 = __half22float2(hp[1]);
        const float2 f2 = __half22float2(hp[2]);
        const float2 f3 = __half22float2(hp[3]);
        acc[0] += f0.x * w; acc[1] += f0.y * w;
        acc[2] += f1.x * w; acc[3] += f1.y * w;
        acc[4] += f2.x * w; acc[5] += f2.y * w;
        acc[6] += f3.x * w; acc[7] += f3.y * w;
    }
    __syncthreads();   // red4 fully consumed above before rewrite
    red4[tid][0] = make_float4(acc[0], acc[1], acc[2], acc[3]);
    red4[tid][1] = make_float4(acc[4], acc[5], acc[6], acc[7]);
    __syncthreads();

    if (tid < C_DIM) {
        const int ch = tid >> 3;
        const int k  = tid & 7;
        float f = 0.f;
        #pragma unroll
        for (int g2 = 0; g2 < 16; ++g2)
            f += rp[(g2 * 16 + ch) * 8 + k];
        out_cf[(long)n * C_DIM + tid] = f;
        chan[tid] = f * W_fit[tid];
    }
    __syncthreads();

    if (tid < DEG) {
        float t = chan[tid] + chan[tid + 64];
        #pragma unroll
        for (int msk = 1; msk <= 32; msk <<= 1)
            t += __shfl_xor(t, msk);
        if (tid == 0)
            out_fit[n] = 1.f / (1.f + __expf(-(t + b_fit[0])));
    }
}

// ---------------------------------------------------------------------------
// Fallback path (ws too small): fp32 two-array gather detector (R2 shape).
// ---------------------------------------------------------------------------
__global__ void precompute_kernel(const float* __restrict__ W_max,
                                  const float* __restrict__ b_max,
                                  const float* __restrict__ W_score,
                                  const float* __restrict__ b_score,
                                  float* __restrict__ combo) {
    const int c = threadIdx.x;
    float acc = 0.f;
    for (int k = 0; k < C_DIM; ++k)
        acc += W_max[c * C_DIM + k] * W_score[k];
    combo[c] = acc;
    __shared__ float red[C_DIM];
    red[c] = b_max[c] * W_score[c];
    __syncthreads();
    for (int off = 64; off > 0; off >>= 1) {
        if (c < off) red[c] += red[c + off];
        __syncthreads();
    }
    if (c == 0) combo[C_DIM] = red[0] + b_score[0];
}

__global__ __launch_bounds__(256)
void detector_f32_kernel(const float* __restrict__ nf,
                         const float* __restrict__ mem,
                         const float* __restrict__ W_score,
                         const float* __restrict__ W_fit,
                         const float* __restrict__ b_fit,
                         const int* __restrict__ neighbors,
                         const float* __restrict__ combo,
                         float* __restrict__ out_cf,
                         float* __restrict__ out_score,
                         float* __restrict__ out_fit) {
    __shared__ float4 red[256];
    __shared__ float  s_raw[DEG];
    __shared__ float  sc[DEG];
    __shared__ float  t1_sh;

    const int tid = threadIdx.x;
    const int n   = blockIdx.x;
    const int q   = tid & 31;
    const int g   = tid >> 5;

    const int4* nb4 = (const int4*)(neighbors + n * DEG + g * 8);
    const int4 nba = nb4[0];
    const int4 nbb = nb4[1];
    const int ids[8] = {nba.x, nba.y, nba.z, nba.w, nbb.x, nbb.y, nbb.z, nbb.w};
    const float4 wsb = ((const float4*)(W_score + C_DIM))[q];
    const float4* nf4  = (const float4*)nf;
    const float4* mem4 = (const float4*)mem;

    float4 v[8];
    float4 mx = make_float4(-INFINITY, -INFINITY, -INFINITY, -INFINITY);
    #pragma unroll
    for (int i = 0; i < 8; ++i) {
        const long node = ids[i];
        float4 vv = nf4[node * 32 + q];
        const float4 b = mem4[node * 32 + q];
        vv.x += b.x; vv.y += b.y; vv.z += b.z; vv.w += b.w;
        v[i] = vv;
        mx.x = fmaxf(mx.x, vv.x); mx.y = fmaxf(mx.y, vv.y);
        mx.z = fmaxf(mx.z, vv.z); mx.w = fmaxf(mx.w, vv.w);
        float p = vv.x * wsb.x + vv.y * wsb.y + vv.z * wsb.z + vv.w * wsb.w;
        p += __shfl_xor(p, 1); p += __shfl_xor(p, 2); p += __shfl_xor(p, 4);
        p += __shfl_xor(p, 8); p += __shfl_xor(p, 16);
        if (q == 0) s_raw[g * 8 + i] = p;
    }
    asm volatile("" ::: "memory");
    red[tid] = mx;
    __syncthreads();
    if (tid < 32) {
        float4 f = red[tid];
        #pragma unroll
        for (int r = 1; r < 8; ++r) {
            const float4 o = red[tid + 32 * r];
            f.x = fmaxf(f.x, o.x); f.y = fmaxf(f.y, o.y);
            f.z = fmaxf(f.z, o.z); f.w = fmaxf(f.w, o.w);
        }
        const float4 wc = ((const float4*)combo)[tid];
        float t1 = f.x * wc.x + f.y * wc.y + f.z * wc.z + f.w * wc.w;
        t1 += __shfl_xor(t1, 1); t1 += __shfl_xor(t1, 2); t1 += __shfl_xor(t1, 4);
        t1 += __shfl_xor(t1, 8); t1 += __shfl_xor(t1, 16);
        if (tid == 0) t1_sh = t1 + combo[C_DIM];
    }
    __syncthreads();
    if (tid < DEG) {
        float s = t1_sh + s_raw[tid];
        s = (s >= 0.f) ? s : NEG_SLOPE * s;
        float m = s;
        #pragma unroll
        for (int msk = 1; msk <= 32; msk <<= 1) m = fmaxf(m, __shfl_xor(m, msk));
        const float ex = __expf(s - m);
        float d = ex;
        #pragma unroll
        for (int msk = 1; msk <= 32; msk <<= 1) d += __shfl_xor(d, msk);
        const float sv = ex / d;
        sc[tid] = sv;
        out_score[n * DEG + tid] = sv;
    }
    __syncthreads();
    float4 acc = make_float4(0.f, 0.f, 0.f, 0.f);
    #pragma unroll
    for (int i = 0; i < 8; ++i) {
        const float w = sc[g * 8 + i];
        acc.x += v[i].x * w; acc.y += v[i].y * w;
        acc.z += v[i].z * w; acc.w += v[i].w * w;
    }
    red[tid] = acc;
    __syncthreads();
    if (tid < 32) {
        float4 f = red[tid];
        #pragma unroll
        for (int r = 1; r < 8; ++r) {
            const float4 o = red[tid + 32 * r];
            f.x += o.x; f.y += o.y; f.z += o.z; f.w += o.w;
        }
        ((float4*)(out_cf + (long)n * C_DIM))[tid] = f;
        const float4 wf = ((const float4*)W_fit)[tid];
        float fp = f.x * wf.x + f.y * wf.y + f.z * wf.z + f.w * wf.w;
        fp += __shfl_xor(fp, 1); fp += __shfl_xor(fp, 2); fp += __shfl_xor(fp, 4);
        fp += __shfl_xor(fp, 8); fp += __shfl_xor(fp, 16);
        if (tid == 0)
            out_fit[n] = 1.f / (1.f + __expf(-(fp + b_fit[0])));
    }
}

extern "C" void kernel_launch(void* const* d_in, const int* in_sizes, int n_in,
                              void* d_out, int out_size, void* d_ws, size_t ws_size,
                              hipStream_t stream) {
    const float* node_features = (const float*)d_in[0];
    const float* memory        = (const float*)d_in[1];
    const float* W_max         = (const float*)d_in[2];
    const float* b_max         = (const float*)d_in[3];
    const float* W_score       = (const float*)d_in[4];
    const float* b_score       = (const float*)d_in[5];
    const float* W_fit         = (const float*)d_in[6];
    const float* b_fit         = (const float*)d_in[7];
    const int*   neighbors     = (const int*)d_in[8];
    // d_in[9] = seg = repeat(arange(nodes), DEG)

    const long n_elem = (long)in_sizes[0];          // n_total * C
    const int  nodes  = in_sizes[8] / DEG;          // 8192
    const long n8     = n_elem / 8;                 // half8 chunks

    float* combo = (float*)d_ws;                    // [129] (+pad to 512)
    __half* sumh = (__half*)(combo + 512);          // [n_elem] fp16, 16B-aligned
    const size_t need = 512 * sizeof(float) + (size_t)n_elem * sizeof(__half);

    float* out_cf    = (float*)d_out;                       // [nodes,128]
    float* out_score = out_cf + (long)nodes * C_DIM;        // [nodes,64]
    float* out_fit   = out_score + (long)nodes * DEG;       // [nodes]

    if (ws_size >= need) {
        fuse_sum_half_kernel<<<2048, 256, 0, stream>>>(
            (const nfloat4*)node_features, (const nfloat4*)memory,
            (nfloat4*)sumh, n8, W_max, b_max, W_score, b_score, combo);
        detector_half_kernel<<<nodes, 256, 0, stream>>>(
            (const float4*)sumh, W_score, W_fit, b_fit, neighbors, combo,
            out_cf, out_score, out_fit);
    } else {
        precompute_kernel<<<1, C_DIM, 0, stream>>>(W_max, b_max, W_score,
                                                   b_score, combo);
        detector_f32_kernel<<<nodes, 256, 0, stream>>>(
            node_features, memory, W_score, W_fit, b_fit, neighbors, combo,
            out_cf, out_score, out_fit);
    }
}